// Round 8
// baseline (195.188 us; speedup 1.0000x reference)
//
#include <hip/hip_runtime.h>
#include <stdint.h>

// Problem constants (B=4, S=2048, H=1024, E=8, TOP_K=2). All I/O fp32.
#define N_TOK 8192
#define H_DIM 1024
#define N_EXP 8
#define MAX_TILES 136   // sum over experts of ceil(cnt_e/128) <= 128 + 7, padded

typedef __bf16 bf16x8 __attribute__((ext_vector_type(8)));
typedef float floatx4 __attribute__((ext_vector_type(4)));

typedef __attribute__((address_space(1))) void GV;
typedef __attribute__((address_space(3))) void LV;

static __device__ __forceinline__ unsigned short f2b(float f) {
    union { float f; unsigned int i; } v; v.f = f;
    unsigned int u = v.i;
    return (unsigned short)((u + 0x7FFFu + ((u >> 16) & 1u)) >> 16);
}
static __device__ __forceinline__ float b2f(unsigned short u) {
    union { unsigned int i; float f; } v; v.i = ((unsigned int)u) << 16; return v.f;
}

// ---------------- K1: fused router (blocks 0..2047) + W repack (blocks 2048..3071) ----------------
__global__ __launch_bounds__(256) void k_front(
    const float* __restrict__ tokens,
    const float* __restrict__ router_w,
    const float* __restrict__ router_b,
    const float* __restrict__ W,
    int* __restrict__ sel, float* __restrict__ w_arr,
    unsigned short* __restrict__ tokb,
    unsigned short* __restrict__ Bp)
{
    const int t = threadIdx.x;

    if (blockIdx.x >= 2048) {
        // ---- repack W[e][h][d] fp32 -> Bp[e][h>>3][d][h&7] bf16 (no LDS) ----
        const int idx = blockIdx.x - 2048;   // 0..1023
        const int kg = idx & 127;
        const int e  = idx >> 7;
        const int d  = t * 4;                // thread owns 4 consecutive d
        const float* src = W + ((size_t)e * H_DIM + kg * 8) * H_DIM + d;
        float col[8][4];
#pragma unroll
        for (int j = 0; j < 8; ++j) {
            float4 v = *(const float4*)(src + (size_t)j * H_DIM);
            col[j][0] = v.x; col[j][1] = v.y; col[j][2] = v.z; col[j][3] = v.w;
        }
        unsigned short* dst = Bp + ((size_t)(e * 128 + kg) * H_DIM + d) * 8;
#pragma unroll
        for (int k = 0; k < 4; ++k) {
            unsigned short v[8];
#pragma unroll
            for (int j = 0; j < 8; ++j) v[j] = f2b(col[j][k]);
            *(uint4*)(dst + (size_t)k * 8) = *(uint4*)v;
        }
        return;
    }

    // ---- router: 1 wave per token, fp32, no atomics; also emit bf16 tokens ----
    const int wave = t >> 6;
    const int lane = t & 63;
    const int n = blockIdx.x * 4 + wave;

    const float* xp = tokens + (size_t)n * H_DIM + lane * 16;
    float x[16];
#pragma unroll
    for (int i = 0; i < 4; ++i) {
        float4 v = *(const float4*)(xp + i * 4);
        x[i * 4 + 0] = v.x; x[i * 4 + 1] = v.y; x[i * 4 + 2] = v.z; x[i * 4 + 3] = v.w;
    }

    {
        unsigned short xb[16];
#pragma unroll
        for (int j = 0; j < 16; ++j) xb[j] = f2b(x[j]);
        unsigned short* dp = tokb + (size_t)n * H_DIM + lane * 16;
        *(uint4*)(dp)     = *(uint4*)(xb);
        *(uint4*)(dp + 8) = *(uint4*)(xb + 8);
    }

    float acc[N_EXP];
#pragma unroll
    for (int e = 0; e < N_EXP; ++e) {
        const float* wp = router_w + e * H_DIM + lane * 16;
        float s = 0.f;
#pragma unroll
        for (int i = 0; i < 4; ++i) {
            float4 v = *(const float4*)(wp + i * 4);
            s += x[i * 4 + 0] * v.x + x[i * 4 + 1] * v.y
               + x[i * 4 + 2] * v.z + x[i * 4 + 3] * v.w;
        }
        acc[e] = s;
    }

#pragma unroll
    for (int e = 0; e < N_EXP; ++e) {
        float a = acc[e];
#pragma unroll
        for (int off = 32; off > 0; off >>= 1) a += __shfl_xor(a, off);
        acc[e] = a;
    }

    if (lane == 0) {
        float lg[N_EXP];
#pragma unroll
        for (int e = 0; e < N_EXP; ++e) lg[e] = acc[e] + router_b[e];
        int e0 = 0;
#pragma unroll
        for (int e = 1; e < N_EXP; ++e) if (lg[e] > lg[e0]) e0 = e;
        int e1 = -1;
#pragma unroll
        for (int e = 0; e < N_EXP; ++e) {
            if (e == e0) continue;
            if (e1 < 0 || lg[e] > lg[e1]) e1 = e;
        }
        // collapsed weights: w0 = p0/(p0+p1) = sigmoid(l0-l1); eps terms < fp32 ulp
        float w0 = 1.f / (1.f + __expf(lg[e1] - lg[e0]));
        float w1 = 1.f - w0;
        sel[n] = e0 | (e1 << 4);
        w_arr[n * 2] = w0;
        w_arr[n * 2 + 1] = w1;
    }
}

// ---------------- K1b: counting sort, one block per expert, 1024 threads ----------------
__global__ __launch_bounds__(1024) void k_scan(
    const int* __restrict__ sel, int* __restrict__ cnt, int* __restrict__ bucket)
{
    __shared__ int ssel[N_TOK + N_TOK / 32];   // padded: idx n -> n + (n>>5)
    __shared__ int sc[1024];
    const int e = blockIdx.x;
    const int t = threadIdx.x;
#pragma unroll
    for (int i = 0; i < 8; ++i) {
        int n = i * 1024 + t;
        ssel[n + (n >> 5)] = sel[n];
    }
    __syncthreads();
    const int base = t * 8;
    int c = 0;
#pragma unroll
    for (int i = 0; i < 8; ++i) {
        int n = base + i;
        int s = ssel[n + (n >> 5)];
        c += ((s & 15) == e) + (((s >> 4) & 15) == e);
    }
    sc[t] = c;
    __syncthreads();
    for (int off = 1; off < 1024; off <<= 1) {
        int v = (t >= off) ? sc[t - off] : 0;
        __syncthreads();
        sc[t] += v;
        __syncthreads();
    }
    int pos = sc[t] - c;   // exclusive prefix
    if (t == 1023) cnt[e] = sc[1023];
#pragma unroll
    for (int i = 0; i < 8; ++i) {
        int n = base + i;
        int s = ssel[n + (n >> 5)];
        if ((s & 15) == e)        bucket[e * N_TOK + pos++] = 2 * n;
        if (((s >> 4) & 15) == e) bucket[e * N_TOK + pos++] = 2 * n + 1;
    }
}

// ---------------- K3: grouped GEMM, M=128 x N=256 tiles, bf16 Y stores ----------------
// Y row layout (per 128-col segment): stored index s = wc*64 + m_lane*4 + j
// holds actual col wc*64 + j*16 + m_lane.
__global__ __launch_bounds__(256, 2) void k_gemm(
    const unsigned short* __restrict__ tokb,
    const unsigned short* __restrict__ Bp,
    const int* __restrict__ cnt, const int* __restrict__ bucket,
    unsigned short* __restrict__ Y)
{
    // flat grid: bid = tile*4 + ntp; decode (e, mt) from cnt[] prefix
    const int ntp = blockIdx.x & 3;        // 256-col group
    const int tile = blockIdx.x >> 2;
    int base = 0, e = 0, mt = -1;
#pragma unroll
    for (int ee = 0; ee < 8; ++ee) {
        int te = (cnt[ee] + 127) >> 7;
        if (tile >= base && tile < base + te) { e = ee; mt = tile - base; }
        base += te;
    }
    if (mt < 0) return;
    const int cnt_local = cnt[e] - mt * 128;

    // As: flat [row][64], XOR-swizzled: (row, part) lives at row*64 + (part^(row&7))*8
    __shared__ __align__(16) unsigned short Asm[128 * 64];        // 16 KB
    __shared__ __align__(16) unsigned short Bsm[2 * 8 * 128 * 8]; // 32 KB, [seg][kg][d][k&7]
    __shared__ int rows[128];

    const int t = threadIdx.x;
    if (t < 128)
        rows[t] = (t < cnt_local) ? bucket[e * N_TOK + mt * 128 + t] : -1;
    __syncthreads();

    const int wv = t >> 6, lane = t & 63;
    const int d0 = ntp * 256;

    // A staging: instr i, lane l covers LDS chunk c = i*256+wv*64+l
    // -> row r = c>>3 = i*32+wv*8+(l>>3), swizzled slot l&7 holds global part p=(l&7)^(r&7)
    const int p_sw = (lane & 7) ^ ((lane >> 3) & 7);
    const unsigned short* aptr[4];
#pragma unroll
    for (int i = 0; i < 4; ++i) {
        int r = i * 32 + wv * 8 + (lane >> 3);
        int rid = rows[r];
        int tok = (rid >= 0) ? (rid >> 1) : 0;   // inactive rows read token 0; masked at store
        aptr[i] = tokb + (size_t)tok * H_DIM + p_sw * 8;
    }
    // B staging per seg: chunk c = i*256+t -> kg' = i*2+(t>>7), d = t&127
    const unsigned short* bbase[2];
#pragma unroll
    for (int seg = 0; seg < 2; ++seg)
        bbase[seg] = Bp + ((size_t)(e * 128 + (t >> 7)) * H_DIM + d0 + seg * 128 + (t & 127)) * 8;

    const int w_row = wv >> 1, w_col = wv & 1;
    const int m_lane = lane & 15, quad = lane >> 4;
    const int r7 = m_lane & 7;

    floatx4 acc[4][2][4];
#pragma unroll
    for (int i = 0; i < 4; ++i)
#pragma unroll
        for (int seg = 0; seg < 2; ++seg)
#pragma unroll
            for (int j = 0; j < 4; ++j) acc[i][seg][j] = (floatx4){0.f, 0.f, 0.f, 0.f};

    for (int kt = 0; kt < H_DIM / 64; ++kt) {
#pragma unroll
        for (int i = 0; i < 4; ++i)
            __builtin_amdgcn_global_load_lds(
                (GV*)(aptr[i] + kt * 64),
                (LV*)(&Asm[i * 2048 + wv * 512]), 16, 0, 0);
#pragma unroll
        for (int seg = 0; seg < 2; ++seg)
#pragma unroll
            for (int i = 0; i < 4; ++i)
                __builtin_amdgcn_global_load_lds(
                    (GV*)(bbase[seg] + (size_t)i * 16384 + (size_t)kt * 65536),
                    (LV*)(&Bsm[seg * 8192 + i * 2048 + wv * 512]), 16, 0, 0);
        __syncthreads();

#pragma unroll
        for (int s = 0; s < 2; ++s) {
            bf16x8 a[4], b[2][4];
#pragma unroll
            for (int i = 0; i < 4; ++i) {
                int row = w_row * 64 + i * 16 + m_lane;
                a[i] = *(const bf16x8*)&Asm[row * 64 + ((s * 4 + quad) ^ r7) * 8];
            }
#pragma unroll
            for (int seg = 0; seg < 2; ++seg)
#pragma unroll
                for (int j = 0; j < 4; ++j)
                    b[seg][j] = *(const bf16x8*)&Bsm[seg * 8192
                        + ((s * 4 + quad) * 128 + w_col * 64 + j * 16 + m_lane) * 8];
#pragma unroll
            for (int i = 0; i < 4; ++i)
#pragma unroll
                for (int seg = 0; seg < 2; ++seg)
#pragma unroll
                    for (int j = 0; j < 4; ++j)
                        acc[i][seg][j] = __builtin_amdgcn_mfma_f32_16x16x32_bf16(
                            a[i], b[seg][j], acc[i][seg][j], 0, 0, 0);
        }
        __syncthreads();
    }

    // epilogue: plain bf16 stores, permuted-within-segment layout (8B per (i,reg,seg))
#pragma unroll
    for (int i = 0; i < 4; ++i) {
        const int lr_base = w_row * 64 + i * 16 + quad * 4;
#pragma unroll
        for (int reg = 0; reg < 4; ++reg) {
            const int lr = lr_base + reg;
            const int rid = rows[lr];
            if (rid >= 0) {
#pragma unroll
                for (int seg = 0; seg < 2; ++seg) {
                    unsigned short v[4];
#pragma unroll
                    for (int j = 0; j < 4; ++j) v[j] = f2b(acc[i][seg][j][reg]);
                    *(uint2*)(Y + (size_t)rid * H_DIM + d0 + seg * 128
                              + w_col * 64 + m_lane * 4) = *(uint2*)v;
                }
            }
        }
    }
}

// ---------------- K4: combine out[n][d] = w0*Y[2n][s(d)] + w1*Y[2n+1][s(d)] ----------------
__global__ __launch_bounds__(256) void k_combine(
    const unsigned short* __restrict__ Y, const float* __restrict__ w_arr,
    float* __restrict__ out)
{
    const int g = blockIdx.x * 256 + threadIdx.x;   // 1,048,576 threads
    const int n = g >> 7;
    const int c = (g & 127) * 8;                    // 8 consecutive stored shorts
    const unsigned short* y0 = Y + (size_t)(2 * n) * H_DIM + c;
    const unsigned short* y1 = y0 + H_DIM;
    uint4 a = *(const uint4*)y0;
    uint4 b = *(const uint4*)y1;
    const unsigned short* pa = (const unsigned short*)&a;
    const unsigned short* pb = (const unsigned short*)&b;
    const float w0 = w_arr[2 * n], w1 = w_arr[2 * n + 1];
    const int seg = c >> 7;
    const int sl0 = c & 127;
    float* op = out + (size_t)n * H_DIM + seg * 128;
#pragma unroll
    for (int k = 0; k < 8; ++k) {
        int sl = sl0 + k;
        int wc = sl >> 6, m = (sl >> 2) & 15, j = sl & 3;
        int d = wc * 64 + j * 16 + m;
        op[d] = w0 * b2f(pa[k]) + w1 * b2f(pb[k]);
    }
}

extern "C" void kernel_launch(void* const* d_in, const int* in_sizes, int n_in,
                              void* d_out, int out_size, void* d_ws, size_t ws_size,
                              hipStream_t stream)
{
    const float* tokens   = (const float*)d_in[0]; // fp32 [8192,1024]
    const float* router_w = (const float*)d_in[1]; // fp32 [8,1024]
    const float* router_b = (const float*)d_in[2]; // fp32 [8]
    const float* W        = (const float*)d_in[3]; // fp32 [8,1024,1024]
    float* out = (float*)d_out;                    // fp32 [8192,1024]

    char* ws = (char*)d_ws;
    int*   cnt    = (int*)(ws);                        // 32 B
    int*   sel    = (int*)(ws + 1024);                 // 32 KB
    float* w_arr  = (float*)(ws + 34816);              // 64 KB
    int*   bucket = (int*)(ws + 100352);               // 256 KB
    unsigned short* tokb = (unsigned short*)(ws + 362496);    // 16 MB bf16 tokens  [ends 17139712]
    unsigned short* Bp   = (unsigned short*)(ws + 17139712);  // 16 MB packed bf16 W [ends 33916928]
    unsigned short* Y    = (unsigned short*)(ws + 33916928);  // 32 MB bf16 per-slot outputs

    k_front  <<<2048 + 1024, 256, 0, stream>>>(tokens, router_w, router_b, W,
                                               sel, w_arr, tokb, Bp);
    k_scan   <<<N_EXP, 1024, 0, stream>>>(sel, cnt, bucket);
    k_gemm   <<<MAX_TILES * 4, 256, 0, stream>>>(tokb, Bp, cnt, bucket, Y);
    k_combine<<<N_TOK * (H_DIM / 8) / 256, 256, 0, stream>>>(Y, w_arr, out);
}